// Round 7
// baseline (290.035 us; speedup 1.0000x reference)
//
#include <hip/hip_runtime.h>
#include <math.h>

#define D 64
#define K 512
#define BLOCK 256
#define ROWS_PB 64              // rows per block (one per lane)
#define KG 4                    // k-groups = waves per block
#define KPG (K / KG)            // 128 codes per k-group
#define SUBK 16                 // codes per register subtile

// Bit-exact emulation of the harness's numpy fp32 reference (validated
// rounds 3-6 at absmax 0.0):
//   dist[i,k] = fp32( fp32(sx[i] + se[k]) - 2*dot[i,k] )   (2*dot exact)
// sx/se = numpy pairwise 8-accumulator sums of squares (contraction OFF),
// dot = single-accumulator fmaf chain, j = 0..63 strictly ascending.
// argmin strict-<, k ascending -> first occurrence.
//
// Architecture (R7): ONE fused kernel. Block = 64 rows x 4 k-groups;
// wave w scans codes [w*128, (w+1)*128) for all 64 rows (one row/lane).
// e-addresses are wave-uniform (readfirstlane-forced) -> s_load through
// the scalar path (~134 MB total), NOT per-lane LDS/VMEM (the e-from-LDS
// designs R4/R6 are return-bandwidth-floored at ~40us). x per block is
// 64 rows = 16 KB -> L1-resident across the 8 subtile passes. In-block
// merge via LDS; hist/loss/finalize fused (R6-validated semaphore).

__device__ __forceinline__ float np_sumsq64_g(const float* v) {
#pragma clang fp contract(off)
    float r[8];
    {
        float4 a = *(const float4*)(v + 0);
        float4 b = *(const float4*)(v + 4);
        r[0] = a.x * a.x; r[1] = a.y * a.y; r[2] = a.z * a.z; r[3] = a.w * a.w;
        r[4] = b.x * b.x; r[5] = b.y * b.y; r[6] = b.z * b.z; r[7] = b.w * b.w;
    }
#pragma unroll
    for (int i = 1; i < 8; ++i) {
        float4 a = *(const float4*)(v + i * 8 + 0);
        float4 b = *(const float4*)(v + i * 8 + 4);
        r[0] = r[0] + a.x * a.x; r[1] = r[1] + a.y * a.y;
        r[2] = r[2] + a.z * a.z; r[3] = r[3] + a.w * a.w;
        r[4] = r[4] + b.x * b.x; r[5] = r[5] + b.y * b.y;
        r[6] = r[6] + b.z * b.z; r[7] = r[7] + b.w * b.w;
    }
    return ((r[0] + r[1]) + (r[2] + r[3])) + ((r[4] + r[5]) + (r[6] + r[7]));
}

__global__ __launch_bounds__(BLOCK) void vq_fused(
    const float* __restrict__ x, const float* __restrict__ emb,
    float* __restrict__ q_out, float* __restrict__ idx_out,
    float* __restrict__ block_sums, int* __restrict__ counts,
    int* __restrict__ done_flag, float* __restrict__ out_loss,
    float* __restrict__ out_perp, float inv_nelem, float inv_rows, int N)
{
    __shared__ float se_s[K];
    __shared__ float2 part[KG][ROWS_PB];
    __shared__ int bi_s[ROWS_PB];
    __shared__ int hist[K];
    __shared__ float red[BLOCK / 64];

    const int tid = threadIdx.x;
    // wave id == k-group; readfirstlane forces SGPR -> e addrs provably uniform
    const int kg = __builtin_amdgcn_readfirstlane(tid >> 6);
    const int r  = tid & 63;
    const int row = blockIdx.x * ROWS_PB + r;
    const bool vrow = row < N;

    // hist zero + se (numpy pairwise ||e_k||^2), 2 codes/thread
    for (int k = tid; k < K; k += BLOCK) {
        hist[k] = 0;
        se_s[k] = np_sumsq64_g(emb + (size_t)k * D);
    }
    __syncthreads();

    const float4* xp = (const float4*)(x + (size_t)row * D);
    const float sx = vrow ? np_sumsq64_g(x + (size_t)row * D) : 0.f;

    const int kbase = kg * KPG;
    float best = INFINITY;
    int bi = kbase;

    if (vrow) {
#pragma unroll 1
        for (int ks = 0; ks < KPG; ks += SUBK) {
            float acc[SUBK];
#pragma unroll
            for (int kk = 0; kk < SUBK; ++kk) acc[kk] = 0.f;

#pragma unroll
            for (int jc = 0; jc < 4; ++jc) {
                // x chunk (16 floats) — L1-resident after first pass
                float4 xv0 = xp[jc * 4 + 0];
                float4 xv1 = xp[jc * 4 + 1];
                float4 xv2 = xp[jc * 4 + 2];
                float4 xv3 = xp[jc * 4 + 3];
#pragma unroll
                for (int kk = 0; kk < SUBK; ++kk) {
                    // wave-uniform address -> s_load_dwordx4 (scalar path)
                    const float4* ek =
                        (const float4*)(emb + (size_t)(kbase + ks + kk) * D)
                        + jc * 4;
                    float4 e0 = ek[0], e1 = ek[1], e2 = ek[2], e3 = ek[3];
                    // j-ascending sequential chain per (row,k) — ref order
                    float a = acc[kk];
                    a = fmaf(xv0.x, e0.x, a);
                    a = fmaf(xv0.y, e0.y, a);
                    a = fmaf(xv0.z, e0.z, a);
                    a = fmaf(xv0.w, e0.w, a);
                    a = fmaf(xv1.x, e1.x, a);
                    a = fmaf(xv1.y, e1.y, a);
                    a = fmaf(xv1.z, e1.z, a);
                    a = fmaf(xv1.w, e1.w, a);
                    a = fmaf(xv2.x, e2.x, a);
                    a = fmaf(xv2.y, e2.y, a);
                    a = fmaf(xv2.z, e2.z, a);
                    a = fmaf(xv2.w, e2.w, a);
                    a = fmaf(xv3.x, e3.x, a);
                    a = fmaf(xv3.y, e3.y, a);
                    a = fmaf(xv3.z, e3.z, a);
                    a = fmaf(xv3.w, e3.w, a);
                    acc[kk] = a;
                }
            }
#pragma unroll
            for (int kk = 0; kk < SUBK; ++kk) {
                // ref rounding: fl(fl(sx+se) - 2*acc); 2*acc exact
                float d = (sx + se_s[kbase + ks + kk]) - 2.0f * acc[kk];
                if (d < best) { best = d; bi = kbase + ks + kk; }  // first-min
            }
        }
    }
    part[kg][r] = make_float2(best, (float)bi);
    __syncthreads();

    // merge 4 k-group partials, kg-ascending == k-ascending -> first occur.
    if (kg == 0 && vrow) {
        float bb = INFINITY; int bbi = 0;
#pragma unroll
        for (int g = 0; g < KG; ++g) {
            float2 p = part[g][r];
            if (p.x < bb) { bb = p.x; bbi = (int)p.y; }
        }
        bi_s[r] = bbi;
        idx_out[row] = (float)bbi;
        atomicAdd(&hist[bbi], 1);
    }
    __syncthreads();

    // epilogue: each thread handles its row's quarter (16 floats)
    float s = 0.f;
    if (vrow) {
        const int b = bi_s[r];
        const float4* ep = (const float4*)(emb + (size_t)b * D) + kg * 4;
        const float4* xq = xp + kg * 4;
        float4* qp = (float4*)(q_out + (size_t)row * D) + kg * 4;
#pragma unroll
        for (int j = 0; j < 4; ++j) {
            float4 xv = xq[j];
            float4 e  = ep[j];
            float dx0 = e.x - xv.x, dx1 = e.y - xv.y;
            float dx2 = e.z - xv.z, dx3 = e.w - xv.w;
            s = fmaf(dx0, dx0, s);
            s = fmaf(dx1, dx1, s);
            s = fmaf(dx2, dx2, s);
            s = fmaf(dx3, dx3, s);
            float4 qs;  // straight-through: x + (q - x), ref rounding
            qs.x = xv.x + dx0; qs.y = xv.y + dx1;
            qs.z = xv.z + dx2; qs.w = xv.w + dx3;
            qp[j] = qs;
        }
    }

    // block loss partial
    for (int off = 32; off; off >>= 1) s += __shfl_down(s, off, 64);
    if (r == 0) red[kg] = s;
    __syncthreads();
    if (tid == 0) {
        float t = 0.f;
#pragma unroll
        for (int w = 0; w < KG; ++w) t += red[w];
        block_sums[blockIdx.x] = t;
    }
    // flush histogram (<=64 nonzero per block)
    for (int k = tid; k < K; k += BLOCK) {
        int hk = hist[k];
        if (hk) atomicAdd(&counts[k], hk);
    }

    // ---- last-block finalize (R6-validated) ----
    __shared__ int is_last;
    __threadfence();
    if (tid == 0)
        is_last = (atomicAdd(done_flag, 1) == (int)gridDim.x - 1);
    __syncthreads();
    if (!is_last) return;
    __threadfence();

    double ls = 0.0;
    for (int i = tid; i < (int)gridDim.x; i += BLOCK)
        ls += (double)block_sums[i];
    double ps = 0.0;
    for (int k = tid; k < K; k += BLOCK) {
        float p = (float)counts[k] * inv_rows;
        ps += (double)(p * logf(p + 1e-10f));
    }
    for (int off = 32; off; off >>= 1) {
        ls += __shfl_down(ls, off, 64);
        ps += __shfl_down(ps, off, 64);
    }
    __shared__ double l4[4], p4[4];
    if (r == 0) { l4[kg] = ls; p4[kg] = ps; }
    __syncthreads();
    if (tid == 0) {
        double L = 0.0, P = 0.0;
#pragma unroll
        for (int w = 0; w < KG; ++w) { L += l4[w]; P += p4[w]; }
        // loss = q_latent + 0.25*e_latent; forward values identical
        *out_loss = 1.25f * (float)(L * (double)inv_nelem);
        *out_perp = expf((float)(-P));
    }
}

extern "C" void kernel_launch(void* const* d_in, const int* in_sizes, int n_in,
                              void* d_out, int out_size, void* d_ws, size_t ws_size,
                              hipStream_t stream) {
    const float* x   = (const float*)d_in[0];
    const float* emb = (const float*)d_in[1];
    const int N = in_sizes[0] / D;                   // 65536 rows
    const int nblocks = (N + ROWS_PB - 1) / ROWS_PB; // 1024

    float* out      = (float*)d_out;
    float* loss_out = out;                  // [0]
    float* q_out    = out + 1;              // [1 .. N*D]
    float* perp_out = out + 1 + (size_t)N * D;
    float* idx_out  = perp_out + 1;         // [.. + N]

    float* block_sums = (float*)d_ws;
    int*   counts     = (int*)((char*)d_ws + (((size_t)nblocks * 4 + 255) & ~(size_t)255));
    int*   done_flag  = counts + K;         // contiguous with counts

    hipMemsetAsync(counts, 0, (K + 1) * sizeof(int), stream);
    vq_fused<<<nblocks, BLOCK, 0, stream>>>(x, emb, q_out, idx_out,
                                            block_sums, counts, done_flag,
                                            loss_out, perp_out,
                                            1.0f / (float)((size_t)N * D),
                                            1.0f / (float)N, N);
}